// Round 4
// baseline (598.671 us; speedup 1.0000x reference)
//
#include <hip/hip_runtime.h>
#include <math.h>

#define DM 256
#define LSEQ 2048
#define BATCH 8
#define NLAYER 8
#define EMAX 192
#define LN_EPS 1e-5f
#define ROWS (BATCH * LSEQ)

typedef float f32x4 __attribute__((ext_vector_type(4)));
typedef short bf16x8 __attribute__((ext_vector_type(8)));
typedef unsigned short u16;
typedef unsigned short u16x4 __attribute__((ext_vector_type(4)));
typedef unsigned short u16x8 __attribute__((ext_vector_type(8)));

union V8 { u16x8 u; bf16x8 b; };

__device__ __forceinline__ float gelu_exact(float v) {
    return 0.5f * v * (1.f + erff(v * 0.70710678118654752f));
}

// split fp32 -> bf16 hi (truncated, exact-subtractable) + bf16 lo (RNE of remainder)
__device__ __forceinline__ void split2(float g, u16& hi, u16& lo) {
    unsigned u = __float_as_uint(g);
    hi = (u16)(u >> 16);
    float fh = __uint_as_float(u & 0xFFFF0000u);
    float r = g - fh;
    unsigned v = __float_as_uint(r);
    v = v + 0x7FFFu + ((v >> 16) & 1u);
    lo = (u16)(v >> 16);
}

// ---------------- pre-split pW (all layers) into bf16 hi/lo ----------------
__global__ void k_prepW(const float* __restrict__ pW, u16* __restrict__ pWh,
                        u16* __restrict__ pWl) {
    int i = (blockIdx.x * blockDim.x + threadIdx.x) * 4;
    float4 w = *(const float4*)&pW[i];
    u16 h0, l0, h1, l1, h2, l2, h3, l3;
    split2(w.x, h0, l0);
    split2(w.y, h1, l1);
    split2(w.z, h2, l2);
    split2(w.w, h3, l3);
    u16x4 vh = {h0, h1, h2, h3};
    u16x4 vl = {l0, l1, l2, l3};
    *(u16x4*)&pWh[i] = vh;
    *(u16x4*)&pWl[i] = vl;
}

// ---------------- prep0: logA/CB all layers, P[0], zero P[1..7] + pooled ----------------
__global__ void k_prep0(const float* __restrict__ x, const float* __restrict__ inW,
                        const float* __restrict__ inb, const float* __restrict__ Ap,
                        const float* __restrict__ Bp, const float* __restrict__ Cp,
                        float* __restrict__ P_all, float* __restrict__ logA_all,
                        float* __restrict__ CB_all, float* __restrict__ pooled) {
    int b = blockIdx.x;
    int c = threadIdx.x;
    float A0 = 1.f / (1.f + expf(-Ap[c]));
    float iw = inW[c], ib = inb[c];
    const float* xb = x + b * LSEQ;
    float pw = 1.f, acc = 0.f;
    for (int t = 0; t <= EMAX; ++t) {
        acc += (xb[t] * iw + ib) * pw;
        pw *= A0;
    }
    P_all[b * DM + c] = acc;
    for (int l = 1; l < NLAYER; ++l) P_all[l * BATCH * DM + b * DM + c] = 0.f;
    for (int e = 0; e < 4; ++e) pooled[e * BATCH * DM + b * DM + c] = 0.f;
    if (b == 0) {
        for (int l = 0; l < NLAYER; ++l) {
            float Al = 1.f / (1.f + expf(-Ap[l * DM + c]));
            logA_all[l * DM + c] = logf(Al);
            CB_all[l * DM + c]   = Bp[l * DM + c] * Cp[l * DM + c];
        }
    }
}

// ---------------- act0: h0 = x*inW+inb ; g0 = split(gelu(D0*h0)) (no tail) ----------------
__global__ void k_act0(const float* __restrict__ x, const float* __restrict__ inW,
                       const float* __restrict__ inb, const float* __restrict__ D0,
                       float* __restrict__ h, u16* __restrict__ gh, u16* __restrict__ gl) {
    int idx = (blockIdx.x * blockDim.x + threadIdx.x) * 8;
    int row = idx >> 8;
    int c = idx & 255;
    float xv = x[row];
    float4 w0 = *(const float4*)&inW[c],   w1 = *(const float4*)&inW[c + 4];
    float4 b0 = *(const float4*)&inb[c],   b1 = *(const float4*)&inb[c + 4];
    float4 d0 = *(const float4*)&D0[c],    d1 = *(const float4*)&D0[c + 4];
    float hv[8];
    hv[0] = xv * w0.x + b0.x; hv[1] = xv * w0.y + b0.y;
    hv[2] = xv * w0.z + b0.z; hv[3] = xv * w0.w + b0.w;
    hv[4] = xv * w1.x + b1.x; hv[5] = xv * w1.y + b1.y;
    hv[6] = xv * w1.z + b1.z; hv[7] = xv * w1.w + b1.w;
    float4 o0 = {hv[0], hv[1], hv[2], hv[3]};
    float4 o1 = {hv[4], hv[5], hv[6], hv[7]};
    *(float4*)&h[idx] = o0;
    *(float4*)&h[idx + 4] = o1;
    float dd[8] = {d0.x, d0.y, d0.z, d0.w, d1.x, d1.y, d1.z, d1.w};
    u16 sh[8], sl[8];
#pragma unroll
    for (int j = 0; j < 8; ++j) split2(gelu_exact(hv[j] * dd[j]), sh[j], sl[j]);
    u16x8 vh = {sh[0], sh[1], sh[2], sh[3], sh[4], sh[5], sh[6], sh[7]};
    u16x8 vl = {sl[0], sl[1], sl[2], sl[3], sl[4], sl[5], sl[6], sl[7]};
    *(u16x8*)&gh[idx] = vh;
    *(u16x8*)&gl[idx] = vl;
}

// ---------------- main per-layer kernel: barrier-free MFMA + fused epilogue ----------------
// block = 256 thr = 4 waves; block tile = 16 rows x 256 cols; wave = 16 rows x 64 cols.
// A-frags from g (global bf16 hi/lo, tail rows recomputed from h); B-frags from pWh/pWl.
__global__ __launch_bounds__(256, 4) void k_mm(
    const float* __restrict__ h, float* __restrict__ hout,
    u16* __restrict__ gh, u16* __restrict__ gl,
    const u16* __restrict__ pWh, const u16* __restrict__ pWl,
    const float* __restrict__ pb, const float* __restrict__ lng,
    const float* __restrict__ lnb,
    const float* __restrict__ Dp, const float* __restrict__ P,
    const float* __restrict__ logA, const float* __restrict__ CB,
    const float* __restrict__ Dn,          // next layer D (null for last)
    const float* __restrict__ logA_next, float* __restrict__ P_next,
    float* __restrict__ pooled, int exitSlot)
{
    __shared__ float Y[16][260];
    __shared__ float csumb[4][256];

    int tid  = threadIdx.x;
    int lane = tid & 63;
    int wv   = tid >> 6;
    int fr   = lane & 15;
    int fq   = lane >> 4;
    int brow = blockIdx.x * 16;
    int b    = brow >> 11;

    int ra = brow + fr;                       // A row for this lane
    int ua = (LSEQ - 1) - (ra & (LSEQ - 1));
    bool tl = (ua <= EMAX);

    const u16* ghp = gh + (size_t)ra * DM + fq * 8;
    const u16* glp = gl + (size_t)ra * DM + fq * 8;
    const u16* bhp = pWh + (size_t)(wv * 64 + fr) * DM + fq * 8;
    const u16* blp = pWl + (size_t)(wv * 64 + fr) * DM + fq * 8;
    const float* hap = h + (size_t)ra * DM + fq * 8;

    f32x4 acc[4];
#pragma unroll
    for (int n = 0; n < 4; ++n) acc[n] = (f32x4){0.f, 0.f, 0.f, 0.f};

#pragma unroll
    for (int ks = 0; ks < 8; ++ks) {
        int ko = ks * 32;
        V8 ah, al;
        ah.u = *(const u16x8*)&ghp[ko];
        al.u = *(const u16x8*)&glp[ko];
        if (tl) {
            // recompute A-frag for tail row from h (+conv tail)
            int kk = ko + fq * 8;
            float4 h0 = *(const float4*)&hap[ko];
            float4 h1 = *(const float4*)&hap[ko + 4];
            float4 d0 = *(const float4*)&Dp[kk];
            float4 d1 = *(const float4*)&Dp[kk + 4];
            float4 la0 = *(const float4*)&logA[kk];
            float4 la1 = *(const float4*)&logA[kk + 4];
            float4 cb0 = *(const float4*)&CB[kk];
            float4 cb1 = *(const float4*)&CB[kk + 4];
            float4 P0  = *(const float4*)&P[b * DM + kk];
            float4 P1  = *(const float4*)&P[b * DM + kk + 4];
            float uf = (float)ua;
            float vv[8];
            vv[0] = h0.x * d0.x + cb0.x * expf(uf * la0.x) * P0.x;
            vv[1] = h0.y * d0.y + cb0.y * expf(uf * la0.y) * P0.y;
            vv[2] = h0.z * d0.z + cb0.z * expf(uf * la0.z) * P0.z;
            vv[3] = h0.w * d0.w + cb0.w * expf(uf * la0.w) * P0.w;
            vv[4] = h1.x * d1.x + cb1.x * expf(uf * la1.x) * P1.x;
            vv[5] = h1.y * d1.y + cb1.y * expf(uf * la1.y) * P1.y;
            vv[6] = h1.z * d1.z + cb1.z * expf(uf * la1.z) * P1.z;
            vv[7] = h1.w * d1.w + cb1.w * expf(uf * la1.w) * P1.w;
            u16 sh[8], sl[8];
#pragma unroll
            for (int j = 0; j < 8; ++j) split2(gelu_exact(vv[j]), sh[j], sl[j]);
            u16x8 th = {sh[0], sh[1], sh[2], sh[3], sh[4], sh[5], sh[6], sh[7]};
            u16x8 tlo = {sl[0], sl[1], sl[2], sl[3], sl[4], sl[5], sl[6], sl[7]};
            ah.u = th;
            al.u = tlo;
        }
        V8 bh[4], bl[4];
#pragma unroll
        for (int n = 0; n < 4; ++n) {
            bh[n].u = *(const u16x8*)&bhp[n * 16 * DM + ko];
            bl[n].u = *(const u16x8*)&blp[n * 16 * DM + ko];
        }
#pragma unroll
        for (int n = 0; n < 4; ++n) {
            acc[n] = __builtin_amdgcn_mfma_f32_16x16x32_bf16(ah.b, bh[n].b, acc[n], 0, 0, 0);
            acc[n] = __builtin_amdgcn_mfma_f32_16x16x32_bf16(ah.b, bl[n].b, acc[n], 0, 0, 0);
            acc[n] = __builtin_amdgcn_mfma_f32_16x16x32_bf16(al.b, bh[n].b, acc[n], 0, 0, 0);
        }
    }

    // ---- epilogue: Y transpose, residual + LN + stores + g_next + pooled + P_next ----
#pragma unroll
    for (int n = 0; n < 4; ++n)
#pragma unroll
        for (int r = 0; r < 4; ++r)
            Y[fq * 4 + r][wv * 64 + n * 16 + fr] = acc[n][r];
    __syncthreads();

    int c0 = lane * 4;
    float4 pbv = *(const float4*)&pb[c0];
    float4 lg  = *(const float4*)&lng[c0];
    float4 lb  = *(const float4*)&lnb[c0];
    float cs0 = 0.f, cs1 = 0.f, cs2 = 0.f, cs3 = 0.f;
#pragma unroll
    for (int i = 0; i < 4; ++i) {
        int lr = wv * 4 + i;
        int gr = brow + lr;
        float4 o2 = *(float4*)&Y[lr][c0];
        float4 hv = *(const float4*)&h[(size_t)gr * DM + c0];
        float y0 = hv.x + o2.x + pbv.x;
        float y1 = hv.y + o2.y + pbv.y;
        float y2 = hv.z + o2.z + pbv.z;
        float y3 = hv.w + o2.w + pbv.w;
        float s  = y0 + y1 + y2 + y3;
        float ss = y0 * y0 + y1 * y1 + y2 * y2 + y3 * y3;
#pragma unroll
        for (int off = 1; off < 64; off <<= 1) {
            s  += __shfl_xor(s, off);
            ss += __shfl_xor(ss, off);
        }
        float mean = s * (1.f / 256.f);
        float var  = ss * (1.f / 256.f) - mean * mean;
        float rstd = rsqrtf(var + LN_EPS);
        float o0 = (y0 - mean) * rstd * lg.x + lb.x;
        float o1 = (y1 - mean) * rstd * lg.y + lb.y;
        float o2o = (y2 - mean) * rstd * lg.z + lb.z;
        float o3 = (y3 - mean) * rstd * lg.w + lb.w;
        float4 ov = {o0, o1, o2o, o3};
        *(float4*)&hout[(size_t)gr * DM + c0] = ov;
        cs0 += o0; cs1 += o1; cs2 += o2o; cs3 += o3;
        if (Dn != nullptr) {
            // write next layer's g (tail-less; tail rows fixed in next k_mm)
            float4 dn = *(const float4*)&Dn[c0];
            u16 gh0, gl0, gh1, gl1, gh2, gl2, gh3, gl3;
            split2(gelu_exact(o0 * dn.x), gh0, gl0);
            split2(gelu_exact(o1 * dn.y), gh1, gl1);
            split2(gelu_exact(o2o * dn.z), gh2, gl2);
            split2(gelu_exact(o3 * dn.w), gh3, gl3);
            u16x4 vh = {gh0, gh1, gh2, gh3};
            u16x4 vl = {gl0, gl1, gl2, gl3};
            *(u16x4*)&gh[(size_t)gr * DM + c0] = vh;
            *(u16x4*)&gl[(size_t)gr * DM + c0] = vl;
        }
        int t = gr & (LSEQ - 1);
        if (P_next != nullptr && t <= EMAX) {
            float tf = (float)t;
            float4 la = *(const float4*)&logA_next[c0];
            atomicAdd(&P_next[b * DM + c0 + 0], o0  * expf(tf * la.x));
            atomicAdd(&P_next[b * DM + c0 + 1], o1  * expf(tf * la.y));
            atomicAdd(&P_next[b * DM + c0 + 2], o2o * expf(tf * la.z));
            atomicAdd(&P_next[b * DM + c0 + 3], o3  * expf(tf * la.w));
        }
    }

    if (exitSlot >= 0) {
        csumb[wv][c0 + 0] = cs0;
        csumb[wv][c0 + 1] = cs1;
        csumb[wv][c0 + 2] = cs2;
        csumb[wv][c0 + 3] = cs3;
        __syncthreads();
        if (tid < 64) {
            int cc = tid * 4;
#pragma unroll
            for (int q = 0; q < 4; ++q) {
                float sm = csumb[0][cc + q] + csumb[1][cc + q] +
                           csumb[2][cc + q] + csumb[3][cc + q];
                atomicAdd(&pooled[exitSlot * (BATCH * DM) + b * DM + cc + q], sm);
            }
        }
    }
}

// ---------------- head ----------------
__global__ void k_head(const float* __restrict__ pooled, const float* __restrict__ hW,
                       const float* __restrict__ hb, float* __restrict__ out) {
    int tid = threadIdx.x;
    if (tid >= 96) return;
    int e = tid / 24;
    int r = tid % 24;
    int b = r / 3;
    int n = r % 3;
    const float* pv = &pooled[e * (BATCH * DM) + b * DM];
    const float* wv = &hW[(e * 3 + n) * DM];
    float acc = 0.f;
    for (int c = 0; c < DM; ++c) acc += pv[c] * wv[c];
    out[e * 24 + b * 3 + n] = acc * (1.f / (float)LSEQ) + hb[e * 3 + n];
}

extern "C" void kernel_launch(void* const* d_in, const int* in_sizes, int n_in,
                              void* d_out, int out_size, void* d_ws, size_t ws_size,
                              hipStream_t stream) {
    const float* x   = (const float*)d_in[0];
    const float* inW = (const float*)d_in[1];
    const float* inb = (const float*)d_in[2];
    const float* Ap  = (const float*)d_in[3];
    const float* Bp  = (const float*)d_in[4];
    const float* Cp  = (const float*)d_in[5];
    const float* Dp  = (const float*)d_in[6];
    const float* pW  = (const float*)d_in[7];
    const float* pb  = (const float*)d_in[8];
    const float* lng = (const float*)d_in[9];
    const float* lnb = (const float*)d_in[10];
    const float* hW  = (const float*)d_in[11];
    const float* hb  = (const float*)d_in[12];
    float* out = (float*)d_out;

    float* ws = (float*)d_ws;
    float* h        = ws;                            // 4194304 f32 (16 MB)
    float* P_all    = h + ROWS * DM;                 // 16384
    float* logA_all = P_all + NLAYER * BATCH * DM;   // 2048
    float* CB_all   = logA_all + NLAYER * DM;        // 2048
    float* pooled   = CB_all + NLAYER * DM;          // 8192
    u16* pWh        = (u16*)(pooled + 4 * BATCH * DM);   // 524288 u16 (1 MB)
    u16* pWl        = pWh + NLAYER * DM * DM;            // 1 MB
    u16* gh         = pWl + NLAYER * DM * DM;            // ROWS*DM u16 (8 MB)
    u16* gl         = gh + ROWS * DM;                    // 8 MB

    k_prepW<<<(NLAYER * DM * DM) / 1024, 256, 0, stream>>>(pW, pWh, pWl);
    k_prep0<<<BATCH, 256, 0, stream>>>(x, inW, inb, Ap, Bp, Cp,
                                       P_all, logA_all, CB_all, pooled);
    k_act0<<<(ROWS * DM) / (256 * 8), 256, 0, stream>>>(x, inW, inb, Dp, h, gh, gl);
    for (int l = 0; l < NLAYER; ++l) {
        int ex = (l == 1) ? 0 : (l == 3) ? 1 : (l == 5) ? 2 : (l == 7) ? 3 : -1;
        bool last = (l == NLAYER - 1);
        const float* Dn  = last ? nullptr : (Dp + (l + 1) * DM);
        const float* lan = last ? nullptr : (logA_all + (l + 1) * DM);
        float* pn        = last ? nullptr : (P_all + (l + 1) * BATCH * DM);
        k_mm<<<ROWS / 16, 256, 0, stream>>>(
            h, h, gh, gl, pWh + l * DM * DM, pWl + l * DM * DM,
            pb + l * DM, lng + l * DM, lnb + l * DM,
            Dp + l * DM, P_all + l * BATCH * DM, logA_all + l * DM, CB_all + l * DM,
            Dn, lan, pn, pooled, ex);
    }
    k_head<<<1, 128, 0, stream>>>(pooled, hW, hb, out);
}

// Round 5
// 300.882 us; speedup vs baseline: 1.9897x; 1.9897x over previous
//
#include <hip/hip_runtime.h>
#include <math.h>

#define DM 256
#define LSEQ 2048
#define BATCH 8
#define NLAYER 8
#define EMAX 192
#define LN_EPS 1e-5f
#define BM 32
#define ROWS (BATCH * LSEQ)

typedef float f32x4 __attribute__((ext_vector_type(4)));
typedef short bf16x8 __attribute__((ext_vector_type(8)));
typedef unsigned short u16;
typedef unsigned short u16x8 __attribute__((ext_vector_type(8)));

union V8 { u16x8 u; bf16x8 b; };

__device__ __forceinline__ float gelu_exact(float v) {
    return 0.5f * v * (1.f + erff(v * 0.70710678118654752f));
}

// split fp32 -> bf16 hi (truncated, exact-subtractable) + bf16 lo (RNE of remainder)
__device__ __forceinline__ void split2(float g, u16& hi, u16& lo) {
    unsigned u = __float_as_uint(g);
    hi = (u16)(u >> 16);
    float fh = __uint_as_float(u & 0xFFFF0000u);
    float r = g - fh;
    unsigned v = __float_as_uint(r);
    v = v + 0x7FFFu + ((v >> 16) & 1u);
    lo = (u16)(v >> 16);
}

// ---------------- pre-split pW into MFMA-fragment-packed bf16 hi/lo ----------------
// packed[e=((cg*8+ks)*64+lane)*8 + j] = pW[col][k], col=(cg>>2)*64+(cg&3)*16+fr,
// k=ks*32+fq*8+j, lane=fq*16+fr.  One layer = 65536 elements.
__global__ void k_prepW(const float* __restrict__ pW, u16* __restrict__ pWh,
                        u16* __restrict__ pWl) {
    int i = blockIdx.x * blockDim.x + threadIdx.x;
    int e = i * 8;
    int l = e >> 16;
    int r = e & 65535;
    int cg = r >> 12;
    int ks = (r >> 9) & 7;
    int lane = (r >> 3) & 63;
    int fq = lane >> 4, fr = lane & 15;
    int col = (cg >> 2) * 64 + (cg & 3) * 16 + fr;
    int k = ks * 32 + fq * 8;
    const float* src = pW + l * 65536 + col * 256 + k;
    float4 w0 = *(const float4*)src;
    float4 w1 = *(const float4*)(src + 4);
    float vv[8] = {w0.x, w0.y, w0.z, w0.w, w1.x, w1.y, w1.z, w1.w};
    u16 sh[8], sl[8];
#pragma unroll
    for (int j = 0; j < 8; ++j) split2(vv[j], sh[j], sl[j]);
    u16x8 vh = {sh[0], sh[1], sh[2], sh[3], sh[4], sh[5], sh[6], sh[7]};
    u16x8 vl = {sl[0], sl[1], sl[2], sl[3], sl[4], sl[5], sl[6], sl[7]};
    *(u16x8*)&pWh[e] = vh;
    *(u16x8*)&pWl[e] = vl;
}

// ---------------- prep0: logA/CB all layers, P[0], zero P[1..7] + pooled ----------------
__global__ void k_prep0(const float* __restrict__ x, const float* __restrict__ inW,
                        const float* __restrict__ inb, const float* __restrict__ Ap,
                        const float* __restrict__ Bp, const float* __restrict__ Cp,
                        float* __restrict__ P_all, float* __restrict__ logA_all,
                        float* __restrict__ CB_all, float* __restrict__ pooled) {
    int b = blockIdx.x;
    int c = threadIdx.x;
    float A0 = 1.f / (1.f + expf(-Ap[c]));
    float iw = inW[c], ib = inb[c];
    const float* xb = x + b * LSEQ;
    float pw = 1.f, acc = 0.f;
    for (int t = 0; t <= EMAX; ++t) {
        acc += (xb[t] * iw + ib) * pw;
        pw *= A0;
    }
    P_all[b * DM + c] = acc;
    for (int l = 1; l < NLAYER; ++l) P_all[l * BATCH * DM + b * DM + c] = 0.f;
    for (int e = 0; e < 4; ++e) pooled[e * BATCH * DM + b * DM + c] = 0.f;
    if (b == 0) {
        for (int l = 0; l < NLAYER; ++l) {
            float Al = 1.f / (1.f + expf(-Ap[l * DM + c]));
            logA_all[l * DM + c] = logf(Al);
            CB_all[l * DM + c]   = Bp[l * DM + c] * Cp[l * DM + c];
        }
    }
}

// ---------------- per-layer: LDS-staged A, packed-global B, fused epilogue ----------------
// 256 thr = 4 waves. Block tile 32 rows x 256 cols; wave tile 32r x 64c (m=2, n=4).
// Stage once (full K), 3 barriers total. Layer 0: h computed from x on the fly.
__global__ __launch_bounds__(256, 2) void k_mm(
    const float* __restrict__ h, float* __restrict__ hout,
    const float* __restrict__ xin, const float* __restrict__ inW,
    const float* __restrict__ inb,
    const u16* __restrict__ pWh, const u16* __restrict__ pWl,
    const float* __restrict__ pb, const float* __restrict__ lng,
    const float* __restrict__ lnb,
    const float* __restrict__ Dp, const float* __restrict__ P,
    const float* __restrict__ logA, const float* __restrict__ CB,
    const float* __restrict__ logA_next, float* __restrict__ P_next,
    float* __restrict__ pooled, int exitSlot)
{
    // stage: Ah [0,32768) with XOR swizzle (hi @0, lo @16384)
    // epilogue aliases: Y f32[32][260] @0 (33280 B), csumb f32[4][256] @33280
    __shared__ __align__(16) char smem[37376];

    int tid  = threadIdx.x;
    int lane = tid & 63;
    int wv   = tid >> 6;
    int fr   = lane & 15;
    int fq   = lane >> 4;
    int brow = blockIdx.x * BM;
    int b    = brow >> 11;

    // ---- stage A: rows brow..brow+31, full K=256, gelu(D*h + tail), split hi/lo ----
    {
        int srow = tid >> 3;
        int gr_s = brow + srow;
        int u_s  = (LSEQ - 1) - (gr_s & (LSEQ - 1));
        bool tail = (u_s <= EMAX);
        float uf = (float)u_s;
        float xv = xin ? xin[gr_s] : 0.f;
        const float* hrow = h + (size_t)gr_s * DM;
#pragma unroll
        for (int i = 0; i < 4; ++i) {
            int c  = (tid & 7) + i * 8;       // 16B chunk index 0..31
            int kk = c * 8;
            float hv[8];
            if (xin) {
                float4 w0 = *(const float4*)&inW[kk], w1 = *(const float4*)&inW[kk + 4];
                float4 b0 = *(const float4*)&inb[kk], b1 = *(const float4*)&inb[kk + 4];
                hv[0] = xv * w0.x + b0.x; hv[1] = xv * w0.y + b0.y;
                hv[2] = xv * w0.z + b0.z; hv[3] = xv * w0.w + b0.w;
                hv[4] = xv * w1.x + b1.x; hv[5] = xv * w1.y + b1.y;
                hv[6] = xv * w1.z + b1.z; hv[7] = xv * w1.w + b1.w;
            } else {
                float4 h0 = *(const float4*)&hrow[kk];
                float4 h1 = *(const float4*)&hrow[kk + 4];
                hv[0] = h0.x; hv[1] = h0.y; hv[2] = h0.z; hv[3] = h0.w;
                hv[4] = h1.x; hv[5] = h1.y; hv[6] = h1.z; hv[7] = h1.w;
            }
            float4 d0 = *(const float4*)&Dp[kk];
            float4 d1 = *(const float4*)&Dp[kk + 4];
            float vv[8];
            vv[0] = hv[0] * d0.x; vv[1] = hv[1] * d0.y;
            vv[2] = hv[2] * d0.z; vv[3] = hv[3] * d0.w;
            vv[4] = hv[4] * d1.x; vv[5] = hv[5] * d1.y;
            vv[6] = hv[6] * d1.z; vv[7] = hv[7] * d1.w;
            if (tail) {
                float4 la0 = *(const float4*)&logA[kk];
                float4 la1 = *(const float4*)&logA[kk + 4];
                float4 cb0 = *(const float4*)&CB[kk];
                float4 cb1 = *(const float4*)&CB[kk + 4];
                float4 P0  = *(const float4*)&P[b * DM + kk];
                float4 P1  = *(const float4*)&P[b * DM + kk + 4];
                vv[0] += cb0.x * expf(uf * la0.x) * P0.x;
                vv[1] += cb0.y * expf(uf * la0.y) * P0.y;
                vv[2] += cb0.z * expf(uf * la0.z) * P0.z;
                vv[3] += cb0.w * expf(uf * la0.w) * P0.w;
                vv[4] += cb1.x * expf(uf * la1.x) * P1.x;
                vv[5] += cb1.y * expf(uf * la1.y) * P1.y;
                vv[6] += cb1.z * expf(uf * la1.z) * P1.z;
                vv[7] += cb1.w * expf(uf * la1.w) * P1.w;
            }
            u16 sh[8], sl[8];
#pragma unroll
            for (int j = 0; j < 8; ++j) split2(gelu_exact(vv[j]), sh[j], sl[j]);
            u16x8 vh = {sh[0], sh[1], sh[2], sh[3], sh[4], sh[5], sh[6], sh[7]};
            u16x8 vl = {sl[0], sl[1], sl[2], sl[3], sl[4], sl[5], sl[6], sl[7]};
            int byte = srow * 512 + ((c ^ (srow & 7)) << 4);
            *(u16x8*)(smem + byte) = vh;
            *(u16x8*)(smem + 16384 + byte) = vl;
        }
    }
    __syncthreads();

    // ---- barrier-free MFMA loop: A from LDS (swizzled), B from packed global ----
    f32x4 acc[2][4];
#pragma unroll
    for (int m = 0; m < 2; ++m)
#pragma unroll
        for (int n = 0; n < 4; ++n) acc[m][n] = (f32x4){0.f, 0.f, 0.f, 0.f};

    const u16* bh_base = pWh + wv * 16384 + lane * 8;
    const u16* bl_base = pWl + wv * 16384 + lane * 8;

#pragma unroll
    for (int ks = 0; ks < 8; ++ks) {
        V8 ah[2], al[2], bh[4], bl[4];
#pragma unroll
        for (int m = 0; m < 2; ++m) {
            int row = m * 16 + fr;
            int byte = row * 512 + (((ks * 4 + fq) ^ (fr & 7)) << 4);
            ah[m].u = *(const u16x8*)(smem + byte);
            al[m].u = *(const u16x8*)(smem + 16384 + byte);
        }
#pragma unroll
        for (int n = 0; n < 4; ++n) {
            int off = (n * 8 + ks) * 512;
            bh[n].u = *(const u16x8*)&bh_base[off];
            bl[n].u = *(const u16x8*)&bl_base[off];
        }
#pragma unroll
        for (int m = 0; m < 2; ++m)
#pragma unroll
            for (int n = 0; n < 4; ++n) {
                acc[m][n] = __builtin_amdgcn_mfma_f32_16x16x32_bf16(ah[m].b, bh[n].b, acc[m][n], 0, 0, 0);
                acc[m][n] = __builtin_amdgcn_mfma_f32_16x16x32_bf16(ah[m].b, bl[n].b, acc[m][n], 0, 0, 0);
                acc[m][n] = __builtin_amdgcn_mfma_f32_16x16x32_bf16(al[m].b, bh[n].b, acc[m][n], 0, 0, 0);
            }
    }
    __syncthreads();   // all LDS-A reads done before Y overwrites

    // ---- epilogue: Y transpose, residual + LN + store + pooled + P_next ----
    float* Y = (float*)smem;           // [32][260]
#pragma unroll
    for (int m = 0; m < 2; ++m)
#pragma unroll
        for (int n = 0; n < 4; ++n)
#pragma unroll
            for (int r = 0; r < 4; ++r)
                Y[(m * 16 + fq * 4 + r) * 260 + wv * 64 + n * 16 + fr] = acc[m][n][r];
    __syncthreads();

    int c0 = lane * 4;
    float4 pbv = *(const float4*)&pb[c0];
    float4 lg  = *(const float4*)&lng[c0];
    float4 lb  = *(const float4*)&lnb[c0];
    float4 wi4, bi4;
    if (xin) { wi4 = *(const float4*)&inW[c0]; bi4 = *(const float4*)&inb[c0]; }
    float cs0 = 0.f, cs1 = 0.f, cs2 = 0.f, cs3 = 0.f;
#pragma unroll
    for (int i = 0; i < 8; ++i) {
        int lr = wv * 8 + i;
        int gr = brow + lr;
        float4 o2 = *(float4*)&Y[lr * 260 + c0];
        float4 hv;
        if (xin) {
            float xv = xin[gr];
            hv.x = xv * wi4.x + bi4.x; hv.y = xv * wi4.y + bi4.y;
            hv.z = xv * wi4.z + bi4.z; hv.w = xv * wi4.w + bi4.w;
        } else {
            hv = *(const float4*)&h[(size_t)gr * DM + c0];
        }
        float y0 = hv.x + o2.x + pbv.x;
        float y1 = hv.y + o2.y + pbv.y;
        float y2 = hv.z + o2.z + pbv.z;
        float y3 = hv.w + o2.w + pbv.w;
        float s  = y0 + y1 + y2 + y3;
        float ss = y0 * y0 + y1 * y1 + y2 * y2 + y3 * y3;
#pragma unroll
        for (int off = 1; off < 64; off <<= 1) {
            s  += __shfl_xor(s, off);
            ss += __shfl_xor(ss, off);
        }
        float mean = s * (1.f / 256.f);
        float var  = ss * (1.f / 256.f) - mean * mean;
        float rstd = rsqrtf(var + LN_EPS);
        float o0 = (y0 - mean) * rstd * lg.x + lb.x;
        float o1 = (y1 - mean) * rstd * lg.y + lb.y;
        float o2o = (y2 - mean) * rstd * lg.z + lb.z;
        float o3 = (y3 - mean) * rstd * lg.w + lb.w;
        float4 ov = {o0, o1, o2o, o3};
        *(float4*)&hout[(size_t)gr * DM + c0] = ov;
        cs0 += o0; cs1 += o1; cs2 += o2o; cs3 += o3;
        int t = gr & (LSEQ - 1);
        if (P_next != nullptr && t <= EMAX) {
            float tf = (float)t;
            float4 la = *(const float4*)&logA_next[c0];
            atomicAdd(&P_next[b * DM + c0 + 0], o0  * expf(tf * la.x));
            atomicAdd(&P_next[b * DM + c0 + 1], o1  * expf(tf * la.y));
            atomicAdd(&P_next[b * DM + c0 + 2], o2o * expf(tf * la.z));
            atomicAdd(&P_next[b * DM + c0 + 3], o3  * expf(tf * la.w));
        }
    }

    if (exitSlot >= 0) {
        float* csumb = (float*)(smem + 33280);   // [4][256]
        csumb[wv * 256 + c0 + 0] = cs0;
        csumb[wv * 256 + c0 + 1] = cs1;
        csumb[wv * 256 + c0 + 2] = cs2;
        csumb[wv * 256 + c0 + 3] = cs3;
        __syncthreads();
        if (tid < 64) {
            int cc = tid * 4;
#pragma unroll
            for (int q = 0; q < 4; ++q) {
                float sm = csumb[cc + q] + csumb[256 + cc + q] +
                           csumb[512 + cc + q] + csumb[768 + cc + q];
                atomicAdd(&pooled[exitSlot * (BATCH * DM) + b * DM + cc + q], sm);
            }
        }
    }
}

// ---------------- head ----------------
__global__ void k_head(const float* __restrict__ pooled, const float* __restrict__ hW,
                       const float* __restrict__ hb, float* __restrict__ out) {
    int tid = threadIdx.x;
    if (tid >= 96) return;
    int e = tid / 24;
    int r = tid % 24;
    int b = r / 3;
    int n = r % 3;
    const float* pv = &pooled[e * (BATCH * DM) + b * DM];
    const float* wv = &hW[(e * 3 + n) * DM];
    float acc = 0.f;
    for (int c = 0; c < DM; ++c) acc += pv[c] * wv[c];
    out[e * 24 + b * 3 + n] = acc * (1.f / (float)LSEQ) + hb[e * 3 + n];
}

extern "C" void kernel_launch(void* const* d_in, const int* in_sizes, int n_in,
                              void* d_out, int out_size, void* d_ws, size_t ws_size,
                              hipStream_t stream) {
    const float* x   = (const float*)d_in[0];
    const float* inW = (const float*)d_in[1];
    const float* inb = (const float*)d_in[2];
    const float* Ap  = (const float*)d_in[3];
    const float* Bp  = (const float*)d_in[4];
    const float* Cp  = (const float*)d_in[5];
    const float* Dp  = (const float*)d_in[6];
    const float* pW  = (const float*)d_in[7];
    const float* pb  = (const float*)d_in[8];
    const float* lng = (const float*)d_in[9];
    const float* lnb = (const float*)d_in[10];
    const float* hW  = (const float*)d_in[11];
    const float* hb  = (const float*)d_in[12];
    float* out = (float*)d_out;

    float* ws = (float*)d_ws;
    float* h        = ws;                            // 4194304 f32 (16 MB)
    float* P_all    = h + ROWS * DM;                 // 16384
    float* logA_all = P_all + NLAYER * BATCH * DM;   // 2048
    float* CB_all   = logA_all + NLAYER * DM;        // 2048
    float* pooled   = CB_all + NLAYER * DM;          // 8192
    u16* pWh        = (u16*)(pooled + 4 * BATCH * DM);   // 524288 u16 (1 MB)
    u16* pWl        = pWh + NLAYER * DM * DM;            // 1 MB

    k_prepW<<<(NLAYER * DM * DM / 8) / 256, 256, 0, stream>>>(pW, pWh, pWl);
    k_prep0<<<BATCH, 256, 0, stream>>>(x, inW, inb, Ap, Bp, Cp,
                                       P_all, logA_all, CB_all, pooled);
    for (int l = 0; l < NLAYER; ++l) {
        int ex = (l == 1) ? 0 : (l == 3) ? 1 : (l == 5) ? 2 : (l == 7) ? 3 : -1;
        bool last = (l == NLAYER - 1);
        const float* lan = last ? nullptr : (logA_all + (l + 1) * DM);
        float* pn        = last ? nullptr : (P_all + (l + 1) * BATCH * DM);
        const float* xi  = (l == 0) ? x : nullptr;
        k_mm<<<ROWS / BM, 256, 0, stream>>>(
            h, h, xi, inW, inb,
            pWh + l * DM * DM, pWl + l * DM * DM,
            pb + l * DM, lng + l * DM, lnb + l * DM,
            Dp + l * DM, P_all + l * BATCH * DM, logA_all + l * DM, CB_all + l * DM,
            lan, pn, pooled, ex);
    }
    k_head<<<1, 128, 0, stream>>>(pooled, hW, hb, out);
}

// Round 6
// 234.278 us; speedup vs baseline: 2.5554x; 1.2843x over previous
//
#include <hip/hip_runtime.h>
#include <math.h>

#define DM 256
#define LSEQ 2048
#define BATCH 8
#define NLAYER 8
#define EMAX 192
#define LN_EPS 1e-5f
#define BM 64
#define ROWS (BATCH * LSEQ)

// LDS layout (bytes)
#define HT_STRIDE 1040              // 260 f32 per row: breaks bank alignment
#define AB_OFF   66560              // 64*1040  -> Ah [64 rows][512 B, XOR-swizzled]
#define AL_OFF   (AB_OFF + 32768)   // Al
#define RED_OFF  (AL_OFF + 32768)   // red [64 rows][4 waves][2] f32
#define SMEM_SZ  (RED_OFF + 2048)   // 134144 B -> 1 block/CU

typedef float f32x4 __attribute__((ext_vector_type(4)));
typedef short bf16x8 __attribute__((ext_vector_type(8)));
typedef unsigned short u16;
typedef unsigned short u16x4 __attribute__((ext_vector_type(4)));
typedef unsigned short u16x8 __attribute__((ext_vector_type(8)));

union V8 { u16x8 u; bf16x8 b; };

__device__ __forceinline__ float gelu_exact(float v) {
    return 0.5f * v * (1.f + erff(v * 0.70710678118654752f));
}

// split fp32 -> bf16 hi (truncated, exact-subtractable) + bf16 lo (RNE of remainder)
__device__ __forceinline__ void split2(float g, u16& hi, u16& lo) {
    unsigned u = __float_as_uint(g);
    hi = (u16)(u >> 16);
    float fh = __uint_as_float(u & 0xFFFF0000u);
    float r = g - fh;
    unsigned v = __float_as_uint(r);
    v = v + 0x7FFFu + ((v >> 16) & 1u);
    lo = (u16)(v >> 16);
}

// ---------------- pre-split pW into MFMA-fragment-packed bf16 hi/lo ----------------
// packed[((cg*8+ks)*64+lane)*8 + j] = pW[col][k], col=(cg>>2)*64+(cg&3)*16+fr,
// k=ks*32+fq*8+j, lane=fq*16+fr.  (verified in r5)
__global__ void k_prepW(const float* __restrict__ pW, u16* __restrict__ pWh,
                        u16* __restrict__ pWl) {
    int i = blockIdx.x * blockDim.x + threadIdx.x;
    int e = i * 8;
    int l = e >> 16;
    int r = e & 65535;
    int cg = r >> 12;
    int ks = (r >> 9) & 7;
    int lane = (r >> 3) & 63;
    int fq = lane >> 4, fr = lane & 15;
    int col = (cg >> 2) * 64 + (cg & 3) * 16 + fr;
    int k = ks * 32 + fq * 8;
    const float* src = pW + l * 65536 + col * 256 + k;
    float4 w0 = *(const float4*)src;
    float4 w1 = *(const float4*)(src + 4);
    float vv[8] = {w0.x, w0.y, w0.z, w0.w, w1.x, w1.y, w1.z, w1.w};
    u16 sh[8], sl[8];
#pragma unroll
    for (int j = 0; j < 8; ++j) split2(vv[j], sh[j], sl[j]);
    u16x8 vh = {sh[0], sh[1], sh[2], sh[3], sh[4], sh[5], sh[6], sh[7]};
    u16x8 vl = {sl[0], sl[1], sl[2], sl[3], sl[4], sl[5], sl[6], sl[7]};
    *(u16x8*)&pWh[e] = vh;
    *(u16x8*)&pWl[e] = vl;
}

// ---------------- prep0: logA/CB all layers, P[0], zero P[1..7] + pooled ----------------
__global__ void k_prep0(const float* __restrict__ x, const float* __restrict__ inW,
                        const float* __restrict__ inb, const float* __restrict__ Ap,
                        const float* __restrict__ Bp, const float* __restrict__ Cp,
                        float* __restrict__ P_all, float* __restrict__ logA_all,
                        float* __restrict__ CB_all, float* __restrict__ pooled) {
    int b = blockIdx.x;
    int c = threadIdx.x;
    float A0 = 1.f / (1.f + expf(-Ap[c]));
    float iw = inW[c], ib = inb[c];
    const float* xb = x + b * LSEQ;
    float pw = 1.f, acc = 0.f;
    for (int t = 0; t <= EMAX; ++t) {
        acc += (xb[t] * iw + ib) * pw;
        pw *= A0;
    }
    P_all[b * DM + c] = acc;
    for (int l = 1; l < NLAYER; ++l) P_all[l * BATCH * DM + b * DM + c] = 0.f;
    for (int e = 0; e < 4; ++e) pooled[e * BATCH * DM + b * DM + c] = 0.f;
    if (b == 0) {
        for (int l = 0; l < NLAYER; ++l) {
            float Al = 1.f / (1.f + expf(-Ap[l * DM + c]));
            logA_all[l * DM + c] = logf(Al);
            CB_all[l * DM + c]   = Bp[l * DM + c] * Cp[l * DM + c];
        }
    }
}

// ---------------- persistent-tile fused kernel: 64 rows through all 8 layers ----------------
// 512 thr = 8 waves (wm=wv>>2 row-half, wn=wv&3 col-slice). h tile lives in LDS (f32),
// residual in registers. Launched twice: blocks 0..27/batch (producers, no tail), then
// blocks 28..31/batch (tail consumers; P[l] complete by then).
__global__ __launch_bounds__(512, 2) void k_fused(
    int bpb, int blkoff,
    const float* __restrict__ x, const float* __restrict__ inW,
    const float* __restrict__ inb,
    const u16* __restrict__ pWh, const u16* __restrict__ pWl,
    const float* __restrict__ Dp_all, const float* __restrict__ pb_all,
    const float* __restrict__ lng_all, const float* __restrict__ lnb_all,
    const float* __restrict__ logA_all, const float* __restrict__ CB_all,
    float* __restrict__ P_all, float* __restrict__ pooled)
{
    __shared__ __align__(16) char smem[SMEM_SZ];

    int tid  = threadIdx.x;
    int lane = tid & 63;
    int wv   = tid >> 6;
    int wm   = wv >> 2;
    int wn   = wv & 3;
    int fr   = lane & 15;
    int fq   = lane >> 4;

    int batch = blockIdx.x / bpb;
    int blk   = blockIdx.x % bpb + blkoff;
    int brow  = batch * LSEQ + blk * BM;
    int b     = batch;

    // stage map
    int srow = tid >> 3;                 // 0..63
    int gr_s = brow + srow;
    int t_s  = gr_s & (LSEQ - 1);
    int u_s  = (LSEQ - 1) - t_s;
    bool tail_s = (u_s <= EMAX);
    float uf = (float)u_s;
    float xv = x[gr_s];

    float hreg[2][4][4];                 // residual h for owned (m,n,r)

    for (int l = 0; l < NLAYER; ++l) {
        const float* Dp  = Dp_all   + l * DM;
        const float* la  = logA_all + l * DM;
        const float* cbp = CB_all   + l * DM;
        const float* Pl  = P_all + (size_t)l * BATCH * DM + b * DM;

        // ---- stage: g = split(gelu(D*h + tail)) into Ah/Al; l==0 also fills hT ----
#pragma unroll
        for (int i = 0; i < 4; ++i) {
            int u  = (tid & 7) + 8 * i;      // 32B chunk 0..31
            int kk = u * 8;
            int hby = srow * HT_STRIDE + u * 32;
            float hv[8];
            if (l == 0) {
                float4 w0 = *(const float4*)&inW[kk], w1 = *(const float4*)&inW[kk + 4];
                float4 b0 = *(const float4*)&inb[kk], b1 = *(const float4*)&inb[kk + 4];
                hv[0] = fmaf(xv, w0.x, b0.x); hv[1] = fmaf(xv, w0.y, b0.y);
                hv[2] = fmaf(xv, w0.z, b0.z); hv[3] = fmaf(xv, w0.w, b0.w);
                hv[4] = fmaf(xv, w1.x, b1.x); hv[5] = fmaf(xv, w1.y, b1.y);
                hv[6] = fmaf(xv, w1.z, b1.z); hv[7] = fmaf(xv, w1.w, b1.w);
                float4 o0 = {hv[0], hv[1], hv[2], hv[3]};
                float4 o1 = {hv[4], hv[5], hv[6], hv[7]};
                *(float4*)(smem + hby) = o0;
                *(float4*)(smem + hby + 16) = o1;
            } else {
                float4 h0 = *(const float4*)(smem + hby);
                float4 h1 = *(const float4*)(smem + hby + 16);
                hv[0] = h0.x; hv[1] = h0.y; hv[2] = h0.z; hv[3] = h0.w;
                hv[4] = h1.x; hv[5] = h1.y; hv[6] = h1.z; hv[7] = h1.w;
            }
            float4 d0 = *(const float4*)&Dp[kk];
            float4 d1 = *(const float4*)&Dp[kk + 4];
            float vv[8];
            vv[0] = hv[0] * d0.x; vv[1] = hv[1] * d0.y;
            vv[2] = hv[2] * d0.z; vv[3] = hv[3] * d0.w;
            vv[4] = hv[4] * d1.x; vv[5] = hv[5] * d1.y;
            vv[6] = hv[6] * d1.z; vv[7] = hv[7] * d1.w;
            if (tail_s) {
                float4 la0 = *(const float4*)&la[kk],  la1 = *(const float4*)&la[kk + 4];
                float4 cb0 = *(const float4*)&cbp[kk], cb1 = *(const float4*)&cbp[kk + 4];
                float4 P0  = *(const float4*)&Pl[kk],  P1  = *(const float4*)&Pl[kk + 4];
                vv[0] += cb0.x * expf(uf * la0.x) * P0.x;
                vv[1] += cb0.y * expf(uf * la0.y) * P0.y;
                vv[2] += cb0.z * expf(uf * la0.z) * P0.z;
                vv[3] += cb0.w * expf(uf * la0.w) * P0.w;
                vv[4] += cb1.x * expf(uf * la1.x) * P1.x;
                vv[5] += cb1.y * expf(uf * la1.y) * P1.y;
                vv[6] += cb1.z * expf(uf * la1.z) * P1.z;
                vv[7] += cb1.w * expf(uf * la1.w) * P1.w;
            }
            u16 sh[8], sl[8];
#pragma unroll
            for (int j = 0; j < 8; ++j) split2(gelu_exact(vv[j]), sh[j], sl[j]);
            u16x8 vh = {sh[0], sh[1], sh[2], sh[3], sh[4], sh[5], sh[6], sh[7]};
            u16x8 vl = {sl[0], sl[1], sl[2], sl[3], sl[4], sl[5], sl[6], sl[7]};
            int aby = srow * 512 + ((u ^ (srow & 7)) << 4);
            *(u16x8*)(smem + AB_OFF + aby) = vh;
            *(u16x8*)(smem + AL_OFF + aby) = vl;
        }
        __syncthreads();   // bar A: Ah/Al (and hT at l==0) ready

        // ---- MFMA: A from LDS, B from packed global (L2-hot) ----
        f32x4 acc[2][4];
#pragma unroll
        for (int m = 0; m < 2; ++m)
#pragma unroll
            for (int n = 0; n < 4; ++n) acc[m][n] = (f32x4){0.f, 0.f, 0.f, 0.f};

        const u16* bhp = pWh + (size_t)l * 65536 + wn * 16384 + lane * 8;
        const u16* blp = pWl + (size_t)l * 65536 + wn * 16384 + lane * 8;

#pragma unroll
        for (int ks = 0; ks < 8; ++ks) {
            V8 ah[2], al[2];
#pragma unroll
            for (int m = 0; m < 2; ++m) {
                int row = wm * 32 + m * 16 + fr;
                int aby = row * 512 + (((ks * 4 + fq) ^ (row & 7)) << 4);
                ah[m].u = *(const u16x8*)(smem + AB_OFF + aby);
                al[m].u = *(const u16x8*)(smem + AL_OFF + aby);
            }
            V8 bh[4], bl[4];
#pragma unroll
            for (int n = 0; n < 4; ++n) {
                bh[n].u = *(const u16x8*)&bhp[(n * 8 + ks) * 512];
                bl[n].u = *(const u16x8*)&blp[(n * 8 + ks) * 512];
            }
#pragma unroll
            for (int m = 0; m < 2; ++m)
#pragma unroll
                for (int n = 0; n < 4; ++n) {
                    acc[m][n] = __builtin_amdgcn_mfma_f32_16x16x32_bf16(ah[m].b, bh[n].b, acc[m][n], 0, 0, 0);
                    acc[m][n] = __builtin_amdgcn_mfma_f32_16x16x32_bf16(ah[m].b, bl[n].b, acc[m][n], 0, 0, 0);
                    acc[m][n] = __builtin_amdgcn_mfma_f32_16x16x32_bf16(al[m].b, bh[n].b, acc[m][n], 0, 0, 0);
                }
        }

        // ---- epilogue p1: y = h + out2 + pb; row sums; cross-wave reduce ----
        if (l == 0) {
#pragma unroll
            for (int m = 0; m < 2; ++m)
#pragma unroll
                for (int n = 0; n < 4; ++n)
#pragma unroll
                    for (int r = 0; r < 4; ++r) {
                        int row = wm * 32 + m * 16 + fq * 4 + r;
                        int col = wn * 64 + n * 16 + fr;
                        hreg[m][n][r] = *(const float*)(smem + row * HT_STRIDE + col * 4);
                    }
        }
        float pbv[4], lgv[4], lbv[4];
#pragma unroll
        for (int n = 0; n < 4; ++n) {
            int col = wn * 64 + n * 16 + fr;
            pbv[n] = pb_all[l * DM + col];
            lgv[n] = lng_all[l * DM + col];
            lbv[n] = lnb_all[l * DM + col];
        }
        float s[2][4], ss[2][4];
#pragma unroll
        for (int m = 0; m < 2; ++m)
#pragma unroll
            for (int r = 0; r < 4; ++r) {
                float sy = 0.f, sy2 = 0.f;
#pragma unroll
                for (int n = 0; n < 4; ++n) {
                    float y = hreg[m][n][r] + acc[m][n][r] + pbv[n];
                    acc[m][n][r] = y;
                    sy += y; sy2 += y * y;
                }
                s[m][r] = sy; ss[m][r] = sy2;
            }
#pragma unroll
        for (int m = 0; m < 2; ++m)
#pragma unroll
            for (int r = 0; r < 4; ++r)
#pragma unroll
                for (int msk = 1; msk < 16; msk <<= 1) {
                    s[m][r]  += __shfl_xor(s[m][r],  msk);
                    ss[m][r] += __shfl_xor(ss[m][r], msk);
                }
        if (fr == 0) {
#pragma unroll
            for (int m = 0; m < 2; ++m)
#pragma unroll
                for (int r = 0; r < 4; ++r) {
                    int row = wm * 32 + m * 16 + fq * 4 + r;
                    *(float*)(smem + RED_OFF + (row * 8 + wn * 2)     * 4) = s[m][r];
                    *(float*)(smem + RED_OFF + (row * 8 + wn * 2 + 1) * 4) = ss[m][r];
                }
        }
        __syncthreads();   // bar B: red ready

        // ---- epilogue p2: LN, write-back, pooled, P_next ----
        float mean[2][4], rstd[2][4];
#pragma unroll
        for (int m = 0; m < 2; ++m)
#pragma unroll
            for (int r = 0; r < 4; ++r) {
                int row = wm * 32 + m * 16 + fq * 4 + r;
                float st = 0.f, sst = 0.f;
#pragma unroll
                for (int w = 0; w < 4; ++w) {
                    st  += *(const float*)(smem + RED_OFF + (row * 8 + w * 2)     * 4);
                    sst += *(const float*)(smem + RED_OFF + (row * 8 + w * 2 + 1) * 4);
                }
                float mu = st * (1.f / 256.f);
                float var = sst * (1.f / 256.f) - mu * mu;
                mean[m][r] = mu;
                rstd[m][r] = rsqrtf(var + LN_EPS);
            }
        int slot = (l == 1) ? 0 : (l == 3) ? 1 : (l == 5) ? 2 : (l == 7) ? 3 : -1;
        bool prod = (l < NLAYER - 1) && (blk <= 3);
        float lanv[4];
        if (prod) {
            const float* lan = logA_all + (l + 1) * DM;
#pragma unroll
            for (int n = 0; n < 4; ++n) lanv[n] = lan[wn * 64 + n * 16 + fr];
        }
        float cs[4] = {0.f, 0.f, 0.f, 0.f};
        float pc[4] = {0.f, 0.f, 0.f, 0.f};
#pragma unroll
        for (int m = 0; m < 2; ++m)
#pragma unroll
            for (int r = 0; r < 4; ++r) {
                int row  = wm * 32 + m * 16 + fq * 4 + r;
                int trow = blk * BM + row;
#pragma unroll
                for (int n = 0; n < 4; ++n) {
                    float o = (acc[m][n][r] - mean[m][r]) * rstd[m][r] * lgv[n] + lbv[n];
                    hreg[m][n][r] = o;
                    int col = wn * 64 + n * 16 + fr;
                    *(float*)(smem + row * HT_STRIDE + col * 4) = o;
                    if (slot >= 0) cs[n] += o;
                    if (prod && trow <= EMAX) pc[n] += o * expf((float)trow * lanv[n]);
                }
            }
        if (slot >= 0) {
#pragma unroll
            for (int n = 0; n < 4; ++n) {
                cs[n] += __shfl_xor(cs[n], 16);
                cs[n] += __shfl_xor(cs[n], 32);
            }
            if (lane < 16) {
#pragma unroll
                for (int n = 0; n < 4; ++n)
                    atomicAdd(&pooled[slot * (BATCH * DM) + b * DM + wn * 64 + n * 16 + lane], cs[n]);
            }
        }
        if (prod) {
#pragma unroll
            for (int n = 0; n < 4; ++n) {
                pc[n] += __shfl_xor(pc[n], 16);
                pc[n] += __shfl_xor(pc[n], 32);
            }
            if (lane < 16) {
#pragma unroll
                for (int n = 0; n < 4; ++n)
                    atomicAdd(&P_all[(size_t)(l + 1) * BATCH * DM + b * DM + wn * 64 + n * 16 + lane], pc[n]);
            }
        }
        __syncthreads();   // bar C: hT/red safe for next layer
    }
}

// ---------------- head ----------------
__global__ void k_head(const float* __restrict__ pooled, const float* __restrict__ hW,
                       const float* __restrict__ hb, float* __restrict__ out) {
    int tid = threadIdx.x;
    if (tid >= 96) return;
    int e = tid / 24;
    int r = tid % 24;
    int b = r / 3;
    int n = r % 3;
    const float* pv = &pooled[e * (BATCH * DM) + b * DM];
    const float* wv = &hW[(e * 3 + n) * DM];
    float acc = 0.f;
    for (int c = 0; c < DM; ++c) acc += pv[c] * wv[c];
    out[e * 24 + b * 3 + n] = acc * (1.f / (float)LSEQ) + hb[e * 3 + n];
}

extern "C" void kernel_launch(void* const* d_in, const int* in_sizes, int n_in,
                              void* d_out, int out_size, void* d_ws, size_t ws_size,
                              hipStream_t stream) {
    const float* x   = (const float*)d_in[0];
    const float* inW = (const float*)d_in[1];
    const float* inb = (const float*)d_in[2];
    const float* Ap  = (const float*)d_in[3];
    const float* Bp  = (const float*)d_in[4];
    const float* Cp  = (const float*)d_in[5];
    const float* Dp  = (const float*)d_in[6];
    const float* pW  = (const float*)d_in[7];
    const float* pb  = (const float*)d_in[8];
    const float* lng = (const float*)d_in[9];
    const float* lnb = (const float*)d_in[10];
    const float* hW  = (const float*)d_in[11];
    const float* hb  = (const float*)d_in[12];
    float* out = (float*)d_out;

    float* ws = (float*)d_ws;
    float* P_all    = ws;                            // 8*8*256 = 16384
    float* logA_all = P_all + NLAYER * BATCH * DM;   // 2048
    float* CB_all   = logA_all + NLAYER * DM;        // 2048
    float* pooled   = CB_all + NLAYER * DM;          // 8192
    u16* pWh        = (u16*)(pooled + 4 * BATCH * DM);   // 524288 u16
    u16* pWl        = pWh + NLAYER * DM * DM;            // 524288 u16

    k_prepW<<<(NLAYER * DM * DM / 8) / 256, 256, 0, stream>>>(pW, pWh, pWl);
    k_prep0<<<BATCH, 256, 0, stream>>>(x, inW, inb, Ap, Bp, Cp,
                                       P_all, logA_all, CB_all, pooled);
    // launch 1: blocks 0..27 per batch (includes all P-producers, no tail rows)
    k_fused<<<BATCH * 28, 512, 0, stream>>>(
        28, 0, x, inW, inb, pWh, pWl, Dp, pb, lng, lnb,
        logA_all, CB_all, P_all, pooled);
    // launch 2: blocks 28..31 per batch (tail consumers; P complete)
    k_fused<<<BATCH * 4, 512, 0, stream>>>(
        4, 28, x, inW, inb, pWh, pWl, Dp, pb, lng, lnb,
        logA_all, CB_all, P_all, pooled);
    k_head<<<1, 128, 0, stream>>>(pooled, hW, hb, out);
}